// Round 1
// baseline (469.718 us; speedup 1.0000x reference)
//
#include <hip/hip_runtime.h>
#include <cstdint>

typedef __bf16 bf16_t;
typedef __bf16 bf16x8 __attribute__((ext_vector_type(8)));
typedef float f32x4 __attribute__((ext_vector_type(4)));

// ---- geometry constants ----
#define BT_   128
#define LTOK  197
#define CIN   768
#define CA_   384
#define TT    16
#define BB    8
#define HH    14
#define NTOK  25088   // 128*196

__device__ __forceinline__ void gl_lds16(const void* g, void* l) {
  __builtin_amdgcn_global_load_lds(
      (const __attribute__((address_space(1))) unsigned int*)g,
      (__attribute__((address_space(3))) unsigned int*)l,
      16, 0, 0);
}

// ---------------- prep: fold 3 convs + identity into one 3x3x3 kernel ----------------
__global__ void prep_weights_kernel(
    const float* __restrict__ c1w, const float* __restrict__ c1b,
    const float* __restrict__ c2w, const float* __restrict__ c2b,
    const float* __restrict__ c3w, const float* __restrict__ c3b,
    float* __restrict__ Weff, float* __restrict__ beff) {
  int a = blockIdx.x * blockDim.x + threadIdx.x;
  if (a >= CA_) return;
  for (int dt = 0; dt < 3; dt++)
    for (int dh = 0; dh < 3; dh++)
      for (int dw = 0; dw < 3; dw++) {
        float v = c3w[a*27 + dt*9 + dh*3 + dw];
        if (dh == 1 && dw == 1) v += c1w[a*3 + dt];
        if (dt == 1)            v += c2w[a*9 + dh*3 + dw];
        v *= (1.0f/3.0f);
        if (dt == 1 && dh == 1 && dw == 1) v += 1.0f;   // + identity
        Weff[a*27 + dt*9 + dh*3 + dw] = v;
      }
  beff[a] = (c1b[a] + c2b[a] + c3b[a]) * (1.0f/3.0f);
}

__global__ void convert_w_kernel(const float* __restrict__ fc1w,
                                 const float* __restrict__ fc2w,
                                 bf16_t* __restrict__ W1,
                                 bf16_t* __restrict__ W2) {
  int i = blockIdx.x * blockDim.x + threadIdx.x;
  if (i < CA_*CIN) { W1[i] = (bf16_t)fc1w[i]; return; }
  i -= CA_*CIN;
  if (i < CIN*CA_) W2[i] = (bf16_t)fc2w[i];
}

__global__ void copy_cls_kernel(const float* __restrict__ x, float* __restrict__ out) {
  int i = blockIdx.x * blockDim.x + threadIdx.x;   // 0 .. 128*768-1
  if (i >= BT_*CIN) return;
  int bt = i / CIN, c = i % CIN;
  size_t off = (size_t)bt * LTOK * CIN + c;
  out[off] = x[off];
}

// ---------------- GEMM1: H0[tok,a] = bf16( x_tokens[tok,:] . fc1_w[a,:] + fc1_b[a] ) ----------------
// A = x tokens (fp32, converted in-register), B = W1 bf16 [384][768] (B^T layout)
__global__ __launch_bounds__(256) void gemm1_kernel(
    const float* __restrict__ x, const bf16_t* __restrict__ W1,
    const float* __restrict__ fc1b, bf16_t* __restrict__ H0) {
  __shared__ bf16_t Alds[128*32];
  __shared__ bf16_t Blds[128*32];
  const int tid  = threadIdx.x;
  const int lane = tid & 63;
  const int wave = tid >> 6;
  const int bm = blockIdx.x, bn = blockIdx.y;

  // A staging: thread stages one row (arow), 16 consecutive k starting at kbase
  const int arow  = tid >> 1;
  const int kbase = (tid & 1) * 16;
  const int tok   = bm*128 + arow;
  const int bt    = tok / 196;
  const float* xrow = x + (size_t)(tok + bt + 1) * CIN + kbase;
  bf16_t* alds_dst = &Alds[arow*32 + kbase];

  // B staging: two 16B chunks/thread via global_load_lds
  const bf16_t* bsrc0 = W1 + (size_t)(bn*128 + (tid>>2))*CIN + (tid&3)*8;
  const bf16_t* bsrc1 = bsrc0 + (size_t)64*CIN;
  bf16_t* blds0 = &Blds[tid*8];
  bf16_t* blds1 = &Blds[(tid+256)*8];

  const int quad = lane >> 4;
  const int r16  = lane & 15;
  const int wm = (wave >> 1) * 64;
  const int wn = (wave & 1) * 64;

  f32x4 acc[4][4] = {};

  for (int k0 = 0; k0 < CIN; k0 += 32) {
    gl_lds16(bsrc0 + k0, blds0);
    gl_lds16(bsrc1 + k0, blds1);
    const float4* xp = (const float4*)(xrow + k0);
    float4 f0 = xp[0], f1 = xp[1], f2 = xp[2], f3 = xp[3];
    bf16x8 p0, p1;
    p0[0]=(bf16_t)f0.x; p0[1]=(bf16_t)f0.y; p0[2]=(bf16_t)f0.z; p0[3]=(bf16_t)f0.w;
    p0[4]=(bf16_t)f1.x; p0[5]=(bf16_t)f1.y; p0[6]=(bf16_t)f1.z; p0[7]=(bf16_t)f1.w;
    p1[0]=(bf16_t)f2.x; p1[1]=(bf16_t)f2.y; p1[2]=(bf16_t)f2.z; p1[3]=(bf16_t)f2.w;
    p1[4]=(bf16_t)f3.x; p1[5]=(bf16_t)f3.y; p1[6]=(bf16_t)f3.z; p1[7]=(bf16_t)f3.w;
    *(bf16x8*)alds_dst       = p0;
    *(bf16x8*)(alds_dst + 8) = p1;
    __syncthreads();
    bf16x8 af[4], bfr[4];
    #pragma unroll
    for (int mt = 0; mt < 4; mt++)
      af[mt] = *(const bf16x8*)&Alds[(wm + mt*16 + r16)*32 + quad*8];
    #pragma unroll
    for (int nt = 0; nt < 4; nt++)
      bfr[nt] = *(const bf16x8*)&Blds[(wn + nt*16 + r16)*32 + quad*8];
    #pragma unroll
    for (int mt = 0; mt < 4; mt++)
      #pragma unroll
      for (int nt = 0; nt < 4; nt++)
        acc[mt][nt] = __builtin_amdgcn_mfma_f32_16x16x32_bf16(af[mt], bfr[nt], acc[mt][nt], 0, 0, 0);
    __syncthreads();
  }

  #pragma unroll
  for (int nt = 0; nt < 4; nt++) {
    const int col = bn*128 + wn + nt*16 + r16;
    const float bias = fc1b[col];
    #pragma unroll
    for (int mt = 0; mt < 4; mt++) {
      const int row0 = bm*128 + wm + mt*16 + quad*4;
      #pragma unroll
      for (int rg = 0; rg < 4; rg++)
        H0[(size_t)(row0 + rg)*CA_ + col] = (bf16_t)(acc[mt][nt][rg] + bias);
    }
  }
}

// ---------------- fused conv: y = conv3d(H0, Weff)+beff ; z = y + proj(y) ----------------
// one block per (b,h,w) column, 384 threads = one channel each, 16 t's in registers
__global__ __launch_bounds__(384) void conv_kernel(
    const bf16_t* __restrict__ H0, const float* __restrict__ Weff,
    const float* __restrict__ beff, const float* __restrict__ projw,
    const float* __restrict__ projb, bf16_t* __restrict__ Z) {
  const int a   = threadIdx.x;
  const int blk = blockIdx.x;            // 0..1567
  const int b   = blk / 196;
  const int hw  = blk % 196;
  const int h   = hw / HH;
  const int w   = hw % HH;

  float Wf[27];
  #pragma unroll
  for (int i = 0; i < 27; i++) Wf[i] = Weff[a*27 + i];
  const float be = beff[a];
  const float p0 = projw[a*3+0], p1 = projw[a*3+1], p2 = projw[a*3+2];
  const float pbv = projb[a];

  float y[TT];
  #pragma unroll
  for (int t = 0; t < TT; t++) y[t] = be;

  const size_t strideT = 196*CA_;
  const bf16_t* gbase = H0 + (size_t)(b*TT)*strideT + (size_t)hw*CA_ + a;

  #pragma unroll
  for (int tau = 0; tau < TT; tau++) {
    float s0 = 0.f, s1 = 0.f, s2 = 0.f;
    const bf16_t* gt = gbase + (size_t)tau*strideT;
    #pragma unroll
    for (int dh = -1; dh <= 1; dh++) {
      #pragma unroll
      for (int dw = -1; dw <= 1; dw++) {
        const int hh2 = h + dh, ww2 = w + dw;
        float gv = 0.f;
        if (hh2 >= 0 && hh2 < HH && ww2 >= 0 && ww2 < HH)
          gv = (float)gt[(dh*HH + dw)*CA_];
        const int wi = (dh+1)*3 + (dw+1);
        s0 += gv * Wf[0*9 + wi];
        s1 += gv * Wf[1*9 + wi];
        s2 += gv * Wf[2*9 + wi];
      }
    }
    if (tau + 1 < TT) y[tau+1] += s0;
    y[tau] += s1;
    if (tau - 1 >= 0) y[tau-1] += s2;
  }

  #pragma unroll
  for (int t = 0; t < TT; t++) {
    const float ym = (t > 0)      ? y[t-1] : 0.f;
    const float yp = (t < TT-1)   ? y[t+1] : 0.f;
    const float z  = y[t] + pbv + p0*ym + p1*y[t] + p2*yp;
    Z[((size_t)(b*TT + t)*196 + hw)*CA_ + a] = (bf16_t)z;
  }
}

// ---------------- GEMM2: out[xrow,c] = x[xrow,c] + Z[tok,:] . fc2_w[c,:] + fc2_b[c] ----------------
__global__ __launch_bounds__(256) void gemm2_kernel(
    const bf16_t* __restrict__ Z, const bf16_t* __restrict__ W2,
    const float* __restrict__ fc2b, const float* __restrict__ x,
    float* __restrict__ out) {
  __shared__ bf16_t Alds[128*32];
  __shared__ bf16_t Blds[128*32];
  const int tid  = threadIdx.x;
  const int lane = tid & 63;
  const int wave = tid >> 6;
  const int bm = blockIdx.x, bn = blockIdx.y;

  const bf16_t* asrc0 = Z  + (size_t)(bm*128 + (tid>>2))*CA_ + (tid&3)*8;
  const bf16_t* asrc1 = asrc0 + (size_t)64*CA_;
  const bf16_t* bsrc0 = W2 + (size_t)(bn*128 + (tid>>2))*CA_ + (tid&3)*8;
  const bf16_t* bsrc1 = bsrc0 + (size_t)64*CA_;
  bf16_t* alds0 = &Alds[tid*8];
  bf16_t* alds1 = &Alds[(tid+256)*8];
  bf16_t* blds0 = &Blds[tid*8];
  bf16_t* blds1 = &Blds[(tid+256)*8];

  const int quad = lane >> 4;
  const int r16  = lane & 15;
  const int wm = (wave >> 1) * 64;
  const int wn = (wave & 1) * 64;

  f32x4 acc[4][4] = {};

  for (int k0 = 0; k0 < CA_; k0 += 32) {
    gl_lds16(asrc0 + k0, alds0);
    gl_lds16(asrc1 + k0, alds1);
    gl_lds16(bsrc0 + k0, blds0);
    gl_lds16(bsrc1 + k0, blds1);
    __syncthreads();
    bf16x8 af[4], bfr[4];
    #pragma unroll
    for (int mt = 0; mt < 4; mt++)
      af[mt] = *(const bf16x8*)&Alds[(wm + mt*16 + r16)*32 + quad*8];
    #pragma unroll
    for (int nt = 0; nt < 4; nt++)
      bfr[nt] = *(const bf16x8*)&Blds[(wn + nt*16 + r16)*32 + quad*8];
    #pragma unroll
    for (int mt = 0; mt < 4; mt++)
      #pragma unroll
      for (int nt = 0; nt < 4; nt++)
        acc[mt][nt] = __builtin_amdgcn_mfma_f32_16x16x32_bf16(af[mt], bfr[nt], acc[mt][nt], 0, 0, 0);
    __syncthreads();
  }

  #pragma unroll
  for (int nt = 0; nt < 4; nt++) {
    const int col = bn*128 + wn + nt*16 + r16;
    const float bias = fc2b[col];
    #pragma unroll
    for (int mt = 0; mt < 4; mt++) {
      #pragma unroll
      for (int rg = 0; rg < 4; rg++) {
        const int tok = bm*128 + wm + mt*16 + quad*4 + rg;
        const int bt  = tok / 196;
        const size_t o = (size_t)(tok + bt + 1)*CIN + col;
        out[o] = x[o] + acc[mt][nt][rg] + bias;
      }
    }
  }
}

extern "C" void kernel_launch(void* const* d_in, const int* in_sizes, int n_in,
                              void* d_out, int out_size, void* d_ws, size_t ws_size,
                              hipStream_t stream) {
  (void)in_sizes; (void)n_in; (void)out_size; (void)ws_size;
  const float* x    = (const float*)d_in[0];
  const float* fc1w = (const float*)d_in[1];
  const float* fc1b = (const float*)d_in[2];
  const float* c1w  = (const float*)d_in[3];
  const float* c1b  = (const float*)d_in[4];
  const float* c2w  = (const float*)d_in[5];
  const float* c2b  = (const float*)d_in[6];
  const float* c3w  = (const float*)d_in[7];
  const float* c3b  = (const float*)d_in[8];
  const float* pw   = (const float*)d_in[9];
  const float* pb   = (const float*)d_in[10];
  const float* fc2w = (const float*)d_in[11];
  const float* fc2b = (const float*)d_in[12];
  float* out = (float*)d_out;

  char* ws = (char*)d_ws;
  bf16_t* W1   = (bf16_t*)(ws);                    // 384*768*2  = 589824
  bf16_t* W2   = (bf16_t*)(ws + 589824);           // 768*384*2  = 589824
  float*  Weff = (float*) (ws + 1179648);          // 384*27*4   = 41472
  float*  beff = (float*) (ws + 1221120);          // 384*4      = 1536
  bf16_t* H0   = (bf16_t*)(ws + 1222656);          // 25088*384*2 = 19267584
  bf16_t* Z    = (bf16_t*)(ws + 20490240);         // 25088*384*2 = 19267584
  // total ws use: 39757824 bytes

  prep_weights_kernel<<<dim3(2), dim3(192), 0, stream>>>(c1w, c1b, c2w, c2b, c3w, c3b, Weff, beff);
  convert_w_kernel<<<dim3(2304), dim3(256), 0, stream>>>(fc1w, fc2w, W1, W2);
  copy_cls_kernel<<<dim3(384), dim3(256), 0, stream>>>(x, out);
  gemm1_kernel<<<dim3(196, 3), dim3(256), 0, stream>>>(x, W1, fc1b, H0);
  conv_kernel<<<dim3(1568), dim3(384), 0, stream>>>(H0, Weff, beff, pw, pb, Z);
  gemm2_kernel<<<dim3(196, 6), dim3(256), 0, stream>>>(Z, W2, fc2b, x, out);
}